// Round 9
// baseline (2708.032 us; speedup 1.0000x reference)
//
#include <hip/hip_runtime.h>
#include <stdint.h>

// CodebookWrapperLinear: out = x @ dequant(w)^T
//   x: (8192,4096) f32 ; codebook: (4,) f32 ; scale: (16384,128,1) f32 ;
//   indexes: (16384,128,32) i32 ; out: (8192,16384) f32
// R9: full within-tile read prefetch. Every ds_read completes >=1 phase
// before its first consuming MFMA (drain hides under the previous phase's
// MFMA), so the LDS pipe and matrix pipe overlap: floor max(MFMA,LDS)
// instead of sum. Register plan: afA/afB (A ping-pong, 32+32) + bvX/bvY
// (16+16) with per-half-iter role swap = 96 operand VGPRs + 128 AGPR acc.
// Next-tile reads are placed immediately AFTER the counted VM6 at ph4/ph8
// (buffer guaranteed there; stages disjoint). Ledger rules verified:
//  - stage@ph_q safe iff target's last read consumed by MFMA at <= q-2
//    (BAR_{q-1} certifies all waves drained it)  -- all 8 stages pass;
//  - rolling vmcnt: 14 outstanding at each VM6, drains exactly through the
//    stage needed for the guarantee (steady 6 left);
//  - operand sets loaded only in their free windows (checked per phase).

typedef unsigned short u16;
typedef __attribute__((ext_vector_type(8))) __bf16 bf16x8;
typedef __attribute__((ext_vector_type(4))) float f32x4;

__device__ __forceinline__ uint32_t f2bf(float f) {
  uint32_t u = __builtin_bit_cast(uint32_t, f);
  return (u + 0x7FFFu + ((u >> 16) & 1u)) >> 16;  // RNE f32 -> bf16
}

__device__ __forceinline__ void gload16(const u16* g, u16* l) {
  __builtin_amdgcn_global_load_lds(
      (__attribute__((address_space(1))) void*)(g),
      (__attribute__((address_space(3))) void*)(l), 16, 0, 0);
}

__device__ __forceinline__ uint32_t sel4(uint32_t b0, uint32_t b1, uint32_t b2,
                                         uint32_t b3, int q) {
  uint32_t lo = (q & 1) ? b1 : b0;
  uint32_t hi = (q & 1) ? b3 : b2;
  return (q & 2) ? hi : lo;
}

// ---- x: f32 -> bf16, 8 elems/thread --------------------------------------
__global__ __launch_bounds__(256) void cvt_x(const float* __restrict__ x,
                                             u16* __restrict__ xb, int n8) {
  int t = blockIdx.x * 256 + threadIdx.x;
  if (t >= n8) return;
  const float4* xp = reinterpret_cast<const float4*>(x) + (size_t)t * 2;
  float4 v0 = xp[0], v1 = xp[1];
  uint4 o;
  o.x = f2bf(v0.x) | (f2bf(v0.y) << 16);
  o.y = f2bf(v0.z) | (f2bf(v0.w) << 16);
  o.z = f2bf(v1.x) | (f2bf(v1.y) << 16);
  o.w = f2bf(v1.z) | (f2bf(v1.w) << 16);
  reinterpret_cast<uint4*>(xb)[t] = o;
}

// ---- w dequant: one thread per 32-elem group -----------------------------
__global__ __launch_bounds__(256) void dequant_w(
    const float* __restrict__ cb, const float* __restrict__ scale,
    const int* __restrict__ idx, u16* __restrict__ w, int ngroups) {
  int t = blockIdx.x * 256 + threadIdx.x;
  if (t >= ngroups) return;
  float m = fmaxf(fmaxf(fabsf(cb[0]), fabsf(cb[1])),
                  fmaxf(fabsf(cb[2]), fabsf(cb[3])));
  m = fmaxf(m, 1e-8f);
  float s = expf(scale[t]) / m;
  uint32_t b0 = f2bf(cb[0] * s), b1 = f2bf(cb[1] * s);
  uint32_t b2 = f2bf(cb[2] * s), b3 = f2bf(cb[3] * s);
  const int4* ip = reinterpret_cast<const int4*>(idx) + (size_t)t * 8;
  uint4* op = reinterpret_cast<uint4*>(w) + (size_t)t * 4;
#pragma unroll
  for (int v = 0; v < 4; ++v) {
    int4 qa = ip[v * 2], qb = ip[v * 2 + 1];
    uint4 o;
    o.x = sel4(b0, b1, b2, b3, qa.x) | (sel4(b0, b1, b2, b3, qa.y) << 16);
    o.y = sel4(b0, b1, b2, b3, qa.z) | (sel4(b0, b1, b2, b3, qa.w) << 16);
    o.z = sel4(b0, b1, b2, b3, qb.x) | (sel4(b0, b1, b2, b3, qb.y) << 16);
    o.w = sel4(b0, b1, b2, b3, qb.z) | (sel4(b0, b1, b2, b3, qb.w) << 16);
    op[v] = o;
  }
}

// ---- 256x256 8-phase bf16 GEMM: C[MxN] = A[MxK] * Bt[NxK]^T --------------
#define BM 256
#define BN 256
#define BK 64

__device__ __forceinline__ void memfence() { asm volatile("" ::: "memory"); }
__device__ __forceinline__ void BARx() {
  memfence();
  __builtin_amdgcn_s_barrier();
  memfence();
}

__global__ void __launch_bounds__(512, 2) gemm256(
    const u16* __restrict__ A, const u16* __restrict__ Bt,
    float* __restrict__ C, int M, int N, int K) {
  // [buf: even/odd K-tile][A|B][256 rows x 64 cols] bf16 = 128 KiB
  __shared__ u16 sm[2][2][BM * BK];

  // T1: XCD-aware bijective swizzle (gridDim.x = 2048, %8 == 0)
  const int nwg = gridDim.x;
  const int cpx = nwg >> 3;
  const int bid = blockIdx.x;
  const int swz = (bid & 7) * cpx + (bid >> 3);
  const int ntn = N / BN;
  const int m0 = (swz / ntn) * BM;
  const int n0 = (swz % ntn) * BN;

  const int tid = threadIdx.x;
  const int lane = tid & 63;
  const int wid = tid >> 6;  // 8 waves: 2 (m: wr) x 4 (n: wc)
  const int wr = wid >> 2;
  const int wc = wid & 3;

  // staging: linear LDS dest (base + lane*16), pre-swizzled global source.
  // LDS (row R, slot p) holds global (row R, slot p ^ (R&7)); R&7=(lane>>3)&7.
  const int srow = wid * 8 + (lane >> 3);
  const int scol = (((lane & 7) ^ ((lane >> 3) & 7)) << 3);
  const u16* gA = A + (size_t)(m0 + srow) * K + scol;
  const u16* gB = Bt + (size_t)(n0 + srow) * K + scol;

  // STAGE one contiguous 128-row half: op 0=A 1=B, h = half, kc = K-col off
#define STAGE(b, op, h, gp, kc)                                   \
  {                                                               \
    u16* d = &sm[(b)][(op)][(h)*8192 + wid * 512];                \
    const u16* g = (gp) + (size_t)((h)*128) * K + (kc);           \
    gload16(g, d);                                                \
    gload16(g + (size_t)64 * K, d + 4096);                        \
  }

  // swizzled LDS fragment reads: row&7 == lane&7 for all fragment rows
  const int swzp0 = (((lane >> 4) ^ (lane & 7)) << 3);
  const int swzp1 = ((((lane >> 4) + 4) ^ (lane & 7)) << 3);
  const int lr = lane & 15;
  const int rAbase = (wr * 64 + lr) * BK;  // + q*8192 selects A half
  const int rBbase = (wc * 32 + lr) * BK;  // + pp*8192 selects B half

  bf16x8 afA[4][2], afB[4][2], bvX[2][2], bvY[2][2];

#define LOADAX(AF, b, q)                                          \
  {                                                               \
    const u16* p = &sm[(b)][0][rAbase + (q)*8192];                \
    AF[0][0] = *(const bf16x8*)(p + swzp0);                       \
    AF[0][1] = *(const bf16x8*)(p + swzp1);                       \
    AF[1][0] = *(const bf16x8*)(p + 1024 + swzp0);                \
    AF[1][1] = *(const bf16x8*)(p + 1024 + swzp1);                \
    AF[2][0] = *(const bf16x8*)(p + 2048 + swzp0);                \
    AF[2][1] = *(const bf16x8*)(p + 2048 + swzp1);                \
    AF[3][0] = *(const bf16x8*)(p + 3072 + swzp0);                \
    AF[3][1] = *(const bf16x8*)(p + 3072 + swzp1);                \
  }
#define LOADBX(BV, b, pp)                                         \
  {                                                               \
    const u16* p = &sm[(b)][1][rBbase + (pp)*8192];               \
    BV[0][0] = *(const bf16x8*)(p + swzp0);                       \
    BV[0][1] = *(const bf16x8*)(p + swzp1);                       \
    BV[1][0] = *(const bf16x8*)(p + 1024 + swzp0);                \
    BV[1][1] = *(const bf16x8*)(p + 1024 + swzp1);                \
  }
#define MFMAQ(q, pp, AF, BV)                                                \
  {                                                                         \
    __builtin_amdgcn_s_setprio(1);                                          \
    _Pragma("unroll") for (int i = 0; i < 4; ++i)                           \
        _Pragma("unroll") for (int j = 0; j < 2; ++j)                       \
            _Pragma("unroll") for (int ks = 0; ks < 2; ++ks)                \
                acc[(q)*4 + i][(pp)*2 + j] =                                \
        __builtin_amdgcn_mfma_f32_16x16x32_bf16(                            \
            AF[i][ks], BV[j][ks], acc[(q)*4 + i][(pp)*2 + j], 0, 0, 0);     \
    __builtin_amdgcn_s_setprio(0);                                          \
  }
#define VM6 asm volatile("s_waitcnt vmcnt(6)" ::: "memory");
#define VM0 asm volatile("s_waitcnt vmcnt(0)" ::: "memory");

  f32x4 acc[8][4];
#pragma unroll
  for (int i = 0; i < 8; ++i)
#pragma unroll
    for (int j = 0; j < 4; ++j) acc[i][j] = f32x4{0.f, 0.f, 0.f, 0.f};

  // ---- prologue: t0 all halves + t1 A0,B0,B1; then pre-read A0,B0(t0) ---
  STAGE(0, 0, 0, gA, (size_t)0)    // t0 A0(b0)
  STAGE(0, 1, 0, gB, (size_t)0)    // t0 B0(b0)
  STAGE(0, 1, 1, gB, (size_t)0)    // t0 B1(b0)
  STAGE(0, 0, 1, gA, (size_t)0)    // t0 A1(b0)
  STAGE(1, 0, 0, gA, (size_t)64)   // t1 A0(b1)
  STAGE(1, 1, 0, gB, (size_t)64)   // t1 B0(b1)
  STAGE(1, 1, 1, gB, (size_t)64)   // t1 B1(b1)
  VM6  // drains t0's 8 loads; 6 left (t1 A0,B0,B1)
  BARx();
  LOADAX(afA, 0, 0)   // A0(t0) -> MFMA ph1
  LOADBX(bvX, 0, 0)   // B0(t0) -> MFMA ph1

  // ---- main loop: iter i computes tiles 2i (b0, ph1-4), 2i+1 (b1, ph5-8).
  // B roles: first half-iter B0->bvX,B1->bvY; second half B0->bvY,B1->bvX.
#pragma unroll 1
  for (int i = 0; i < 31; ++i) {
    const size_t cT1 = (size_t)(2 * i + 1) * 64;  // buf1's late A1 half
    const size_t cT2 = (size_t)(2 * i + 2) * 64;  // -> b0
    const size_t cT3 = (size_t)(2 * i + 3) * 64;  // -> b1
    // ph1: read B1(b0)->bvY [use ph2]; stage A1(b1) [last read prev-ph6,
    //      consumed prev-MFMA7, BAR8 certified]
    LOADBX(bvY, 0, 1)
    STAGE(1, 0, 1, gA, cT1)
    BARx(); MFMAQ(0, 0, afA, bvX)
    // ph2: read A1(b0)->afB [use ph3; afB free since prev-ph8]
    LOADAX(afB, 0, 1)
    BARx(); MFMAQ(0, 1, afA, bvY)
    // ph3: stage A0,B0(b0)<-t2i+2 [A0/B0 last read prev-ph8, consumed
    //      MFMA1, BAR2 certified]
    STAGE(0, 0, 0, gA, cT2) STAGE(0, 1, 0, gB, cT2)
    BARx(); MFMAQ(1, 1, afB, bvY)
    // ph4: stage B1(b0) [read ph1, consumed MFMA2, BAR3 certified]; W4
    //      guarantees buf1 (drains through ph1's stage); THEN read
    //      A0(b1)->afA, B0(b1)->bvY [use ph5; drain under MFMA4]
    STAGE(0, 1, 1, gB, cT2)
    VM6
    LOADAX(afA, 1, 0)
    LOADBX(bvY, 1, 0)
    BARx(); MFMAQ(1, 0, afB, bvX)
    // ph5: read B1(b1)->bvX [use ph6; bvX free after MFMA4]; stage A1(b0)
    //      [read ph2, consumed MFMA3, BAR4 certified]
    LOADBX(bvX, 1, 1)
    STAGE(0, 0, 1, gA, cT2)
    BARx(); MFMAQ(0, 0, afA, bvY)
    // ph6: read A1(b1)->afB [use ph7; afB free after MFMA4]
    LOADAX(afB, 1, 1)
    BARx(); MFMAQ(0, 1, afA, bvX)
    // ph7: stage A0,B0(b1)<-t2i+3 [read ph4, consumed MFMA5, BAR6 certified]
    STAGE(1, 0, 0, gA, cT3) STAGE(1, 1, 0, gB, cT3)
    BARx(); MFMAQ(1, 1, afB, bvX)
    // ph8: stage B1(b1) [read ph5, consumed MFMA6, BAR7 certified]; W8
    //      guarantees buf0<-t2i+2 (drains through ph5's stage); THEN read
    //      A0(b0)->afA, B0(b0)->bvX of next iter [use ph1']
    STAGE(1, 1, 1, gB, cT3)
    VM6
    LOADAX(afA, 0, 0)
    LOADBX(bvX, 0, 0)
    BARx(); MFMAQ(1, 0, afB, bvY)
  }

  // ---- peeled final iter (tiles 62,63): only ph1 stage; VM0 at W4 -------
  {
    const size_t cT1 = (size_t)63 * 64;
    LOADBX(bvY, 0, 1)
    STAGE(1, 0, 1, gA, cT1)   // completes buf1 <- t63
    BARx(); MFMAQ(0, 0, afA, bvX)
    LOADAX(afB, 0, 1)
    BARx(); MFMAQ(0, 1, afA, bvY)
    BARx(); MFMAQ(1, 1, afB, bvY)
    VM0                       // drain t63's remaining stages
    LOADAX(afA, 1, 0)
    LOADBX(bvY, 1, 0)
    BARx(); MFMAQ(1, 0, afB, bvX)
    LOADBX(bvX, 1, 1)
    BARx(); MFMAQ(0, 0, afA, bvY)
    LOADAX(afB, 1, 1)
    BARx(); MFMAQ(0, 1, afA, bvX)
    BARx(); MFMAQ(1, 1, afB, bvX)
    BARx(); MFMAQ(1, 0, afB, bvY)
  }

  // ---- epilogue: C/D layout col=lane&15, row=(lane>>4)*4+reg ------------
  const int crow0 = m0 + wr * 64 + ((lane >> 4) << 2);
  const int ccol0 = n0 + wc * 32 + (lane & 15);
#pragma unroll
  for (int q = 0; q < 2; ++q)
#pragma unroll
    for (int mi = 0; mi < 4; ++mi)
#pragma unroll
      for (int r = 0; r < 4; ++r) {
        float* cp = C + (size_t)(crow0 + q * 128 + mi * 16 + r) * N + ccol0;
#pragma unroll
        for (int pp = 0; pp < 2; ++pp)
#pragma unroll
          for (int j = 0; j < 2; ++j)
            cp[pp * 128 + j * 16] = acc[q * 4 + mi][pp * 2 + j][r];
      }
}

extern "C" void kernel_launch(void* const* d_in, const int* in_sizes, int n_in,
                              void* d_out, int out_size, void* d_ws,
                              size_t ws_size, hipStream_t stream) {
  const float* x = (const float*)d_in[0];
  const float* cb = (const float*)d_in[1];
  const float* scale = (const float*)d_in[2];
  const int* idx = (const int*)d_in[3];
  float* out = (float*)d_out;

  constexpr int M = 4 * 2048;  // B*S
  constexpr int N = 16384;     // OUT
  constexpr int K = 4096;      // IN

  u16* xb = (u16*)d_ws;          // M*K bf16 = 64 MiB
  u16* wb = xb + (size_t)M * K;  // N*K bf16 = 128 MiB

  const int n8 = M * K / 8;
  cvt_x<<<dim3(n8 / 256), dim3(256), 0, stream>>>(x, xb, n8);
  const int ngroups = N * (K / 32);
  dequant_w<<<dim3(ngroups / 256), dim3(256), 0, stream>>>(cb, scale, idx, wb,
                                                           ngroups);
  gemm256<<<dim3((M / BM) * (N / BN)), dim3(512), 0, stream>>>(xb, wb, out, M,
                                                               N, K);
}

// Round 10
// 1044.766 us; speedup vs baseline: 2.5920x; 2.5920x over previous
//
#include <hip/hip_runtime.h>
#include <stdint.h>

// CodebookWrapperLinear: out = x @ dequant(w)^T
//   x: (8192,4096) f32 ; codebook: (4,) f32 ; scale: (16384,128,1) f32 ;
//   indexes: (16384,128,32) i32 ; out: (8192,16384) f32
// R10: R8 (verified 953us gemm, MfmaUtil 58, zero spill) with ONE change:
// C epilogue uses __builtin_nontemporal_store. Theory: the 512MB f32 C
// stream evicts the 256MB LLC, flushing B panels between row-sweeps ->
// 2.165GB HBM FETCH (~770us at measured BW) co-limits the kernel. NT
// stores keep A/B (192MB unique) LLC-resident. Zero register/schedule risk.

typedef unsigned short u16;
typedef __attribute__((ext_vector_type(8))) __bf16 bf16x8;
typedef __attribute__((ext_vector_type(4))) float f32x4;

__device__ __forceinline__ uint32_t f2bf(float f) {
  uint32_t u = __builtin_bit_cast(uint32_t, f);
  return (u + 0x7FFFu + ((u >> 16) & 1u)) >> 16;  // RNE f32 -> bf16
}

__device__ __forceinline__ void gload16(const u16* g, u16* l) {
  __builtin_amdgcn_global_load_lds(
      (__attribute__((address_space(1))) void*)(g),
      (__attribute__((address_space(3))) void*)(l), 16, 0, 0);
}

__device__ __forceinline__ uint32_t sel4(uint32_t b0, uint32_t b1, uint32_t b2,
                                         uint32_t b3, int q) {
  uint32_t lo = (q & 1) ? b1 : b0;
  uint32_t hi = (q & 1) ? b3 : b2;
  return (q & 2) ? hi : lo;
}

// ---- x: f32 -> bf16, 8 elems/thread --------------------------------------
__global__ __launch_bounds__(256) void cvt_x(const float* __restrict__ x,
                                             u16* __restrict__ xb, int n8) {
  int t = blockIdx.x * 256 + threadIdx.x;
  if (t >= n8) return;
  const float4* xp = reinterpret_cast<const float4*>(x) + (size_t)t * 2;
  float4 v0 = xp[0], v1 = xp[1];
  uint4 o;
  o.x = f2bf(v0.x) | (f2bf(v0.y) << 16);
  o.y = f2bf(v0.z) | (f2bf(v0.w) << 16);
  o.z = f2bf(v1.x) | (f2bf(v1.y) << 16);
  o.w = f2bf(v1.z) | (f2bf(v1.w) << 16);
  reinterpret_cast<uint4*>(xb)[t] = o;
}

// ---- w dequant: one thread per 32-elem group -----------------------------
__global__ __launch_bounds__(256) void dequant_w(
    const float* __restrict__ cb, const float* __restrict__ scale,
    const int* __restrict__ idx, u16* __restrict__ w, int ngroups) {
  int t = blockIdx.x * 256 + threadIdx.x;
  if (t >= ngroups) return;
  float m = fmaxf(fmaxf(fabsf(cb[0]), fabsf(cb[1])),
                  fmaxf(fabsf(cb[2]), fabsf(cb[3])));
  m = fmaxf(m, 1e-8f);
  float s = expf(scale[t]) / m;
  uint32_t b0 = f2bf(cb[0] * s), b1 = f2bf(cb[1] * s);
  uint32_t b2 = f2bf(cb[2] * s), b3 = f2bf(cb[3] * s);
  const int4* ip = reinterpret_cast<const int4*>(idx) + (size_t)t * 8;
  uint4* op = reinterpret_cast<uint4*>(w) + (size_t)t * 4;
#pragma unroll
  for (int v = 0; v < 4; ++v) {
    int4 qa = ip[v * 2], qb = ip[v * 2 + 1];
    uint4 o;
    o.x = sel4(b0, b1, b2, b3, qa.x) | (sel4(b0, b1, b2, b3, qa.y) << 16);
    o.y = sel4(b0, b1, b2, b3, qa.z) | (sel4(b0, b1, b2, b3, qa.w) << 16);
    o.z = sel4(b0, b1, b2, b3, qb.x) | (sel4(b0, b1, b2, b3, qb.y) << 16);
    o.w = sel4(b0, b1, b2, b3, qb.z) | (sel4(b0, b1, b2, b3, qb.w) << 16);
    op[v] = o;
  }
}

// ---- 256x256 8-phase bf16 GEMM: C[MxN] = A[MxK] * Bt[NxK]^T --------------
#define BM 256
#define BN 256
#define BK 64

__device__ __forceinline__ void memfence() { asm volatile("" ::: "memory"); }
__device__ __forceinline__ void BARx() {
  memfence();
  __builtin_amdgcn_s_barrier();
  memfence();
}

__global__ void __launch_bounds__(512, 2) gemm256(
    const u16* __restrict__ A, const u16* __restrict__ Bt,
    float* __restrict__ C, int M, int N, int K) {
  // [buf: even/odd K-tile][A|B][256 rows x 64 cols] bf16 = 128 KiB
  __shared__ u16 sm[2][2][BM * BK];

  // T1: XCD-aware bijective swizzle (gridDim.x = 2048, %8 == 0)
  const int nwg = gridDim.x;
  const int cpx = nwg >> 3;
  const int bid = blockIdx.x;
  const int swz = (bid & 7) * cpx + (bid >> 3);
  const int ntn = N / BN;
  const int m0 = (swz / ntn) * BM;
  const int n0 = (swz % ntn) * BN;

  const int tid = threadIdx.x;
  const int lane = tid & 63;
  const int wid = tid >> 6;  // 8 waves: 2 (m: wr) x 4 (n: wc)
  const int wr = wid >> 2;
  const int wc = wid & 3;

  // staging: linear LDS dest (base + lane*16), pre-swizzled global source.
  // LDS (row R, slot p) holds global (row R, slot p ^ (R&7)); R&7=(lane>>3)&7.
  const int srow = wid * 8 + (lane >> 3);
  const int scol = (((lane & 7) ^ ((lane >> 3) & 7)) << 3);
  const u16* gA = A + (size_t)(m0 + srow) * K + scol;
  const u16* gB = Bt + (size_t)(n0 + srow) * K + scol;

  // STAGE one contiguous 128-row half: op 0=A 1=B, h = half, kc = K-col off
#define STAGE(b, op, h, gp, kc)                                   \
  {                                                               \
    u16* d = &sm[(b)][(op)][(h)*8192 + wid * 512];                \
    const u16* g = (gp) + (size_t)((h)*128) * K + (kc);           \
    gload16(g, d);                                                \
    gload16(g + (size_t)64 * K, d + 4096);                        \
  }

  // swizzled LDS fragment reads: row&7 == lane&7 for all fragment rows
  const int swzp0 = (((lane >> 4) ^ (lane & 7)) << 3);
  const int swzp1 = ((((lane >> 4) + 4) ^ (lane & 7)) << 3);
  const int lr = lane & 15;
  const int rAbase = (wr * 64 + lr) * BK;  // + q*8192 selects A half
  const int rBbase = (wc * 32 + lr) * BK;  // + pp*8192 selects B half

  bf16x8 af[4][2], bv0[2][2], bv1[2][2];

#define LOADA(b, q)                                               \
  {                                                               \
    const u16* p = &sm[(b)][0][rAbase + (q)*8192];                \
    af[0][0] = *(const bf16x8*)(p + swzp0);                       \
    af[0][1] = *(const bf16x8*)(p + swzp1);                       \
    af[1][0] = *(const bf16x8*)(p + 1024 + swzp0);                \
    af[1][1] = *(const bf16x8*)(p + 1024 + swzp1);                \
    af[2][0] = *(const bf16x8*)(p + 2048 + swzp0);                \
    af[2][1] = *(const bf16x8*)(p + 2048 + swzp1);                \
    af[3][0] = *(const bf16x8*)(p + 3072 + swzp0);                \
    af[3][1] = *(const bf16x8*)(p + 3072 + swzp1);                \
  }
#define LOADBX(BV, b, pp)                                         \
  {                                                               \
    const u16* p = &sm[(b)][1][rBbase + (pp)*8192];               \
    BV[0][0] = *(const bf16x8*)(p + swzp0);                       \
    BV[0][1] = *(const bf16x8*)(p + swzp1);                       \
    BV[1][0] = *(const bf16x8*)(p + 1024 + swzp0);                \
    BV[1][1] = *(const bf16x8*)(p + 1024 + swzp1);                \
  }
#define MFMAQ(q, pp, BV)                                                    \
  {                                                                         \
    __builtin_amdgcn_s_setprio(1);                                          \
    _Pragma("unroll") for (int i = 0; i < 4; ++i)                           \
        _Pragma("unroll") for (int j = 0; j < 2; ++j)                       \
            _Pragma("unroll") for (int ks = 0; ks < 2; ++ks)                \
                acc[(q)*4 + i][(pp)*2 + j] =                                \
        __builtin_amdgcn_mfma_f32_16x16x32_bf16(                            \
            af[i][ks], BV[j][ks], acc[(q)*4 + i][(pp)*2 + j], 0, 0, 0);     \
    __builtin_amdgcn_s_setprio(0);                                          \
  }
#define VM6 asm volatile("s_waitcnt vmcnt(6)" ::: "memory");
#define VM0 asm volatile("s_waitcnt vmcnt(0)" ::: "memory");

  f32x4 acc[8][4];
#pragma unroll
  for (int i = 0; i < 8; ++i)
#pragma unroll
    for (int j = 0; j < 4; ++j) acc[i][j] = f32x4{0.f, 0.f, 0.f, 0.f};

  // ---- prologue: tile0 all halves, then tile1 A0,B0,B1 (A1 at ph1) ------
  STAGE(0, 0, 0, gA, (size_t)0)    // t0 A0(b0)
  STAGE(0, 1, 0, gB, (size_t)0)    // t0 B0(b0)
  STAGE(0, 1, 1, gB, (size_t)0)    // t0 B1(b0)
  STAGE(0, 0, 1, gA, (size_t)0)    // t0 A1(b0)
  STAGE(1, 0, 0, gA, (size_t)64)   // t1 A0(b1)
  STAGE(1, 1, 0, gB, (size_t)64)   // t1 B0(b1)
  STAGE(1, 1, 1, gB, (size_t)64)   // t1 B1(b1)
  VM6  // 8 oldest of 14 = tile0 fully landed
  BARx();

  // ---- main loop: iter i computes tiles 2i (b0), 2i+1 (b1) --------------
  // Phase p = [reads_p | stages_p | (VM) | BAR | MFMA_p]; one barrier/phase.
  // bv1 read one phase early (last in issue order): its drain hides under
  // the current phase's MFMA; ph2/ph6 are read-free.
#pragma unroll 1
  for (int i = 0; i < 31; ++i) {
    const size_t cT1 = (size_t)(2 * i + 1) * 64;  // tile 2i+1 final half
    const size_t cT2 = (size_t)(2 * i + 2) * 64;  // -> b0
    const size_t cT3 = (size_t)(2 * i + 3) * 64;  // -> b1
    // ph1: reads A0,B0(b0) then B1(b0) early; stage A1(b1) of t2i+1
    LOADA(0, 0) LOADBX(bv0, 0, 0) LOADBX(bv1, 0, 1)
    STAGE(1, 0, 1, gA, cT1)
    BARx(); MFMAQ(0, 0, bv0)
    // ph2: read-free (bv1 prefetched in ph1)
    BARx(); MFMAQ(0, 1, bv1)
    // ph3: reads A1(b0); stage A0(b0)+B0(b0) of t2i+2 (last read ph1)
    LOADA(0, 1)
    STAGE(0, 0, 0, gA, cT2) STAGE(0, 1, 0, gB, cT2)
    BARx(); MFMAQ(1, 1, bv1)
    // ph4: no reads; stage B1(b0) (last read ph1, +3); W4 -> t2i+1 ready
    STAGE(0, 1, 1, gB, cT2)
    VM6
    BARx(); MFMAQ(1, 0, bv0)
    // ph5: reads A0,B0(b1) then B1(b1) early; stage A1(b0) (last read ph3)
    LOADA(1, 0) LOADBX(bv0, 1, 0) LOADBX(bv1, 1, 1)
    STAGE(0, 0, 1, gA, cT2)
    BARx(); MFMAQ(0, 0, bv0)
    // ph6: read-free
    BARx(); MFMAQ(0, 1, bv1)
    // ph7: reads A1(b1); stage A0(b1)+B0(b1) of t2i+3 (last read ph5)
    LOADA(1, 1)
    STAGE(1, 0, 0, gA, cT3) STAGE(1, 1, 0, gB, cT3)
    BARx(); MFMAQ(1, 1, bv1)
    // ph8: no reads; stage B1(b1) (last read ph5, +3); W8 -> t2i+2 ready
    STAGE(1, 1, 1, gB, cT3)
    VM6
    BARx(); MFMAQ(1, 0, bv0)
  }

  // ---- peeled final iter (tiles 62,63): only ph1 stage; VM0 at W4 -------
  {
    const size_t cT1 = (size_t)63 * 64;
    LOADA(0, 0) LOADBX(bv0, 0, 0) LOADBX(bv1, 0, 1)
    STAGE(1, 0, 1, gA, cT1)
    BARx(); MFMAQ(0, 0, bv0)
    BARx(); MFMAQ(0, 1, bv1)
    LOADA(0, 1)
    BARx(); MFMAQ(1, 1, bv1)
    VM0
    BARx(); MFMAQ(1, 0, bv0)
    LOADA(1, 0) LOADBX(bv0, 1, 0) LOADBX(bv1, 1, 1)
    BARx(); MFMAQ(0, 0, bv0)
    BARx(); MFMAQ(0, 1, bv1)
    LOADA(1, 1)
    BARx(); MFMAQ(1, 1, bv1)
    BARx(); MFMAQ(1, 0, bv0)
  }

  // ---- epilogue: C/D layout col=lane&15, row=(lane>>4)*4+reg ------------
  // Nontemporal stores: C (512MB f32) must not evict A/B panels from LLC.
  const int crow0 = m0 + wr * 64 + ((lane >> 4) << 2);
  const int ccol0 = n0 + wc * 32 + (lane & 15);
#pragma unroll
  for (int q = 0; q < 2; ++q)
#pragma unroll
    for (int mi = 0; mi < 4; ++mi)
#pragma unroll
      for (int r = 0; r < 4; ++r) {
        float* cp = C + (size_t)(crow0 + q * 128 + mi * 16 + r) * N + ccol0;
#pragma unroll
        for (int pp = 0; pp < 2; ++pp)
#pragma unroll
          for (int j = 0; j < 2; ++j)
            __builtin_nontemporal_store(acc[q * 4 + mi][pp * 2 + j][r],
                                        cp + pp * 128 + j * 16);
      }
}

extern "C" void kernel_launch(void* const* d_in, const int* in_sizes, int n_in,
                              void* d_out, int out_size, void* d_ws,
                              size_t ws_size, hipStream_t stream) {
  const float* x = (const float*)d_in[0];
  const float* cb = (const float*)d_in[1];
  const float* scale = (const float*)d_in[2];
  const int* idx = (const int*)d_in[3];
  float* out = (float*)d_out;

  constexpr int M = 4 * 2048;  // B*S
  constexpr int N = 16384;     // OUT
  constexpr int K = 4096;      // IN

  u16* xb = (u16*)d_ws;          // M*K bf16 = 64 MiB
  u16* wb = xb + (size_t)M * K;  // N*K bf16 = 128 MiB

  const int n8 = M * K / 8;
  cvt_x<<<dim3(n8 / 256), dim3(256), 0, stream>>>(x, xb, n8);
  const int ngroups = N * (K / 32);
  dequant_w<<<dim3(ngroups / 256), dim3(256), 0, stream>>>(cb, scale, idx, wb,
                                                           ngroups);
  gemm256<<<dim3((M / BM) * (N / BN)), dim3(512), 0, stream>>>(xb, wb, out, M,
                                                               N, K);
}